// Round 6
// baseline (914.418 us; speedup 1.0000x reference)
//
#include <hip/hip_runtime.h>
#include <hip/hip_bf16.h>

#define SLOW 32
#define MSG 16
#define TSTEPS 4
#define BATCH 8
#define NI0 256
#define NO0 128
#define NI1 128
#define NO1 64

__device__ __forceinline__ float rcpf(float x) { return __builtin_amdgcn_rcpf(x); }
__device__ __forceinline__ float sigf(float x) { return rcpf(1.f + __expf(-x)); }
__device__ __forceinline__ float tanh_apx(float x) {
    float xc = fminf(fmaxf(x, -15.f), 15.f);
    float e = __expf(-2.f * xc);
    return (1.f - e) * rcpf(1.f + e);
}

// ---------------------------------------------------------------------------
// prep: transpose Wh (32x128) -> WhT (128x32), Wf/Wb (32x16) -> WfT/WbT (16x32)
// ---------------------------------------------------------------------------
__global__ void k_prep(const float* __restrict__ Wh, const float* __restrict__ Wf,
                       const float* __restrict__ Wb,
                       float* __restrict__ WhT, float* __restrict__ WfT,
                       float* __restrict__ WbT) {
    int i = blockIdx.x * 256 + threadIdx.x;
    if (i < 128 * SLOW) {
        int j = i >> 7, k = i & 127;
        WhT[k * SLOW + j] = Wh[i];
    }
    if (i < MSG * SLOW) {
        int j = i >> 4, m = i & 15;
        WfT[m * SLOW + j] = Wf[i];
        WbT[m * SLOW + j] = Wb[i];
    }
}

// ---------------------------------------------------------------------------
// merge: for slow channels s<16, replace h/c with mean over batch (in place)
// ---------------------------------------------------------------------------
__global__ void k_merge(float* __restrict__ h0, float* __restrict__ c0,
                        float* __restrict__ h1, float* __restrict__ c1) {
    int idx = blockIdx.x * blockDim.x + threadIdx.x;
    const int P0 = NO0 * NI0;
    const int P1 = NO1 * NI1;
    const int N0 = 16 * P0;
    const int N1 = 16 * P1;
    float* h; float* c; int s, p, plane;
    if (idx < N0) { h = h0; c = c0; s = idx / P0; p = idx % P0; plane = P0; }
    else {
        idx -= N0;
        if (idx >= N1) return;
        h = h1; c = c1; s = idx / P1; p = idx % P1; plane = P1;
    }
    size_t base = (size_t)(s * BATCH) * plane + p;
    float sh = 0.f, sc = 0.f;
#pragma unroll
    for (int b = 0; b < BATCH; b++) { sh += h[base + (size_t)b * plane]; sc += c[base + (size_t)b * plane]; }
    sh *= 0.125f; sc *= 0.125f;
#pragma unroll
    for (int b = 0; b < BATCH; b++) { h[base + (size_t)b * plane] = sh; c[base + (size_t)b * plane] = sc; }
}

// ---------------------------------------------------------------------------
// Layer 0: block = (b,no,half), 256 threads = 4 s-groups x 64 lanes,
// each thread handles 2 cells (cl and cl+64) -> 128 cells/block.
// Weight LDS broadcast amortized over 128 cells (8 instr/cell-micro).
// ---------------------------------------------------------------------------
__global__ __launch_bounds__(256) void k_l0(
    const float* __restrict__ inp, const float* __restrict__ Wi,
    const float* __restrict__ WhT, const float* __restrict__ b_lstm,
    const float* __restrict__ WfT, const float* __restrict__ bf,
    const float* __restrict__ ln_fs, const float* __restrict__ ln_fb,
    float* __restrict__ h0g, float* __restrict__ c0g,
    const float* __restrict__ nb1, float* __restrict__ nf_part, int t) {
    int q = blockIdx.x & 1;
    int no = (blockIdx.x >> 1) & 127;
    int b = blockIdx.x >> 8;
    int tid = threadIdx.x;
    int cl = tid & 63;
    int sgu = __builtin_amdgcn_readfirstlane(tid >> 6);  // 0..3, wave-uniform

    __shared__ __align__(16) float WhL[128 * SLOW];   // 16 KB
    __shared__ __align__(16) float WfL[MSG * SLOW];   // 2 KB
    __shared__ float h_lds[128 * 33];                 // 16.9 KB (fm aliases this)
    __shared__ float gsh[128];
    __shared__ float red[4][MSG];

    // stage weights (coalesced, linear LDS)
#pragma unroll
    for (int i = tid; i < 128 * SLOW / 4; i += 256)
        ((float4*)WhL)[i] = ((const float4*)WhT)[i];
    if (tid < MSG * SLOW / 4)
        ((float4*)WfL)[tid] = ((const float4*)WfT)[tid];

    if (tid < 128) {
        float acc = b_lstm[tid];
        const float* nbr = nb1 + ((size_t)b * NO0 + no) * MSG;
#pragma unroll
        for (int m = 0; m < MSG; m++) acc += nbr[m] * Wi[(MSG + m) * 128 + tid];
        gsh[tid] = acc;
    }

    int cellA = q * 128 + cl;
    int cellB = cellA + 64;
    float miA = inp[((size_t)t * BATCH + b) * NI0 + cellA];
    float miB = inp[((size_t)t * BATCH + b) * NI0 + cellB];
    const size_t SS = (size_t)BATCH * NO0 * NI0;
    size_t baseA = ((size_t)b * NO0 + no) * NI0 + cellA;
    size_t baseB = baseA + 64;

    float cA[8], cB[8];
#pragma unroll
    for (int k = 0; k < 8; k++) {
        int s = sgu + 4 * k;
        h_lds[cl * 33 + s] = h0g[(size_t)s * SS + baseA];
        h_lds[(cl + 64) * 33 + s] = h0g[(size_t)s * SS + baseB];
        cA[k] = c0g[(size_t)s * SS + baseA];
        cB[k] = c0g[(size_t)s * SS + baseB];
    }
    __syncthreads();

    float hallA[SLOW], hallB[SLOW];
#pragma unroll
    for (int micro = 0; micro < 2; micro++) {
#pragma unroll
        for (int j = 0; j < SLOW; j++) {
            hallA[j] = h_lds[cl * 33 + j];
            hallB[j] = h_lds[(cl + 64) * 33 + j];
        }
        __syncthreads();
#pragma unroll
        for (int k = 0; k < 8; k++) {
            int s = sgu + 4 * k;
            float g0 = gsh[s], g1 = gsh[SLOW + s], g2 = gsh[2 * SLOW + s], g3 = gsh[3 * SLOW + s];
            float wi0 = Wi[s], wi1 = Wi[SLOW + s], wi2 = Wi[2 * SLOW + s], wi3 = Wi[3 * SLOW + s];
            float aA0 = g0 + miA * wi0, aA1 = g1 + miA * wi1, aA2 = g2 + miA * wi2, aA3 = g3 + miA * wi3;
            float aB0 = g0 + miB * wi0, aB1 = g1 + miB * wi1, aB2 = g2 + miB * wi2, aB3 = g3 + miB * wi3;
#pragma unroll
            for (int j = 0; j < SLOW; j += 4) {
                float4 w0 = *(const float4*)&WhL[(s)*SLOW + j];
                float4 w1 = *(const float4*)&WhL[(SLOW + s) * SLOW + j];
                float4 w2 = *(const float4*)&WhL[(2 * SLOW + s) * SLOW + j];
                float4 w3 = *(const float4*)&WhL[(3 * SLOW + s) * SLOW + j];
                float x0 = hallA[j], x1 = hallA[j + 1], x2 = hallA[j + 2], x3 = hallA[j + 3];
                aA0 += x0 * w0.x + x1 * w0.y + x2 * w0.z + x3 * w0.w;
                aA1 += x0 * w1.x + x1 * w1.y + x2 * w1.z + x3 * w1.w;
                aA2 += x0 * w2.x + x1 * w2.y + x2 * w2.z + x3 * w2.w;
                aA3 += x0 * w3.x + x1 * w3.y + x2 * w3.z + x3 * w3.w;
                float y0 = hallB[j], y1 = hallB[j + 1], y2 = hallB[j + 2], y3 = hallB[j + 3];
                aB0 += y0 * w0.x + y1 * w0.y + y2 * w0.z + y3 * w0.w;
                aB1 += y0 * w1.x + y1 * w1.y + y2 * w1.z + y3 * w1.w;
                aB2 += y0 * w2.x + y1 * w2.y + y2 * w2.z + y3 * w2.w;
                aB3 += y0 * w3.x + y1 * w3.y + y2 * w3.z + y3 * w3.w;
            }
            float cnA = sigf(aA1) * cA[k] + sigf(aA0) * tanh_apx(aA2);
            cA[k] = cnA;
            float hvA = sigf(aA3) * tanh_apx(cnA);
            h_lds[cl * 33 + s] = hvA;
            float cnB = sigf(aB1) * cB[k] + sigf(aB0) * tanh_apx(aB2);
            cB[k] = cnB;
            float hvB = sigf(aB3) * tanh_apx(cnB);
            h_lds[(cl + 64) * 33 + s] = hvB;
            if (micro == 1) {
                h0g[(size_t)s * SS + baseA] = hvA;
                h0g[(size_t)s * SS + baseB] = hvB;
                c0g[(size_t)s * SS + baseA] = cnA;
                c0g[(size_t)s * SS + baseB] = cnB;
            }
        }
        __syncthreads();
    }

    // final h for fm
#pragma unroll
    for (int j = 0; j < SLOW; j++) {
        hallA[j] = h_lds[cl * 33 + j];
        hallB[j] = h_lds[(cl + 64) * 33 + j];
    }
    __syncthreads();  // all hall reads done before alias overwrite

    float* fmL = h_lds;  // alias: 128*17 <= 128*33
#pragma unroll
    for (int mm = 0; mm < 4; mm++) {
        int m = sgu * 4 + mm;
        float aA = bf[m], aB = aA;
#pragma unroll
        for (int j = 0; j < SLOW; j += 4) {
            float4 w = *(const float4*)&WfL[m * SLOW + j];
            aA += hallA[j] * w.x + hallA[j + 1] * w.y + hallA[j + 2] * w.z + hallA[j + 3] * w.w;
            aB += hallB[j] * w.x + hallB[j + 1] * w.y + hallB[j + 2] * w.z + hallB[j + 3] * w.w;
        }
        fmL[cl * 17 + m] = aA;
        fmL[(cl + 64) * 17 + m] = aB;
    }
    __syncthreads();

    float v[MSG];
    {
        float fmA[MSG], fmB[MSG];
#pragma unroll
        for (int m = 0; m < MSG; m++) {
            fmA[m] = fmL[cl * 17 + m];
            fmB[m] = fmL[(cl + 64) * 17 + m];
        }
        float meanA = 0.f, meanB = 0.f;
#pragma unroll
        for (int m = 0; m < MSG; m++) { meanA += fmA[m]; meanB += fmB[m]; }
        meanA *= (1.f / MSG); meanB *= (1.f / MSG);
        float varA = 0.f, varB = 0.f;
#pragma unroll
        for (int m = 0; m < MSG; m++) {
            float dA = fmA[m] - meanA; varA += dA * dA;
            float dB = fmB[m] - meanB; varB += dB * dB;
        }
        varA *= (1.f / MSG); varB *= (1.f / MSG);
        float rsA = rsqrtf(varA + 1e-6f), rsB = rsqrtf(varB + 1e-6f);
#pragma unroll
        for (int m = 0; m < MSG; m++) {
            float s = ln_fs[m], bb = ln_fb[m];
            v[m] = ((fmA[m] - meanA) * rsA + (fmB[m] - meanB) * rsB) * s + 2.f * bb;
        }
    }

    // raw partial sum over block (each cell counted 4x -> k_xf divides /1024)
    int lane = tid & 63, wv = tid >> 6;
#pragma unroll
    for (int m = 0; m < MSG; m++) {
        float x = v[m];
#pragma unroll
        for (int d = 1; d < 64; d <<= 1) x += __shfl_xor(x, d);
        if (lane == 0) red[wv][m] = x;
    }
    __syncthreads();
    if (tid < MSG) {
        float a = red[0][tid] + red[1][tid] + red[2][tid] + red[3][tid];
        nf_part[(((size_t)b * NO0 + no) * 2 + q) * MSG + tid] = a;
    }
}

// ---------------------------------------------------------------------------
// k_xf: xf1T[b][k][no0] = sum_m nf[b,no0,m] * Wi[m,k], nf = sum of 2 parts /1024
// ---------------------------------------------------------------------------
__global__ __launch_bounds__(128) void k_xf(const float* __restrict__ nf_part,
                                            const float* __restrict__ Wi,
                                            float* __restrict__ xf1T) {
    int b = blockIdx.x >> 7;
    int k = blockIdx.x & 127;
    int no = threadIdx.x;
    float nf[MSG];
#pragma unroll
    for (int m = 0; m < MSG; m++) nf[m] = 0.f;
    const float* p = nf_part + ((size_t)b * NO0 + no) * 2 * MSG;
#pragma unroll
    for (int qm = 0; qm < 2 * MSG; qm++) nf[qm & 15] += p[qm];
    float a = 0.f;
#pragma unroll
    for (int m = 0; m < MSG; m++) a += nf[m] * Wi[m * 128 + k];
    xf1T[((size_t)b * 128 + k) * NO0 + no] = a * (1.f / 1024.f);
}

// ---------------------------------------------------------------------------
// Layer 1: block = (b,no), 256 threads = 4 s-groups x 64 lanes, 2 cells/thread
// (all 128 cells of the (b,no) group in one block).
// ---------------------------------------------------------------------------
__global__ __launch_bounds__(256) void k_l1(
    const float* __restrict__ Wi, const float* __restrict__ WhT,
    const float* __restrict__ b_lstm,
    const float* __restrict__ WfT, const float* __restrict__ bf,
    const float* __restrict__ ln_fs, const float* __restrict__ ln_fb,
    const float* __restrict__ WbT, const float* __restrict__ bwb,
    const float* __restrict__ ln_bs, const float* __restrict__ ln_bb,
    float* __restrict__ h1g, float* __restrict__ c1g,
    const float* __restrict__ xf1T, const float* __restrict__ gradP,
    const float* __restrict__ ohP,
    float* __restrict__ bm_g, float* __restrict__ outsum) {
    int no = blockIdx.x & 63;
    int b = blockIdx.x >> 6;
    int tid = threadIdx.x;
    int cl = tid & 63;
    int sgu = __builtin_amdgcn_readfirstlane(tid >> 6);

    __shared__ __align__(16) float WhL[128 * SLOW];
    __shared__ __align__(16) float WfL[MSG * SLOW];
    __shared__ __align__(16) float WbL[MSG * SLOW];
    __shared__ float h_lds[128 * 33];                 // msg exchange aliases this
    __shared__ float gsh[128];
    __shared__ float red[4];

#pragma unroll
    for (int i = tid; i < 128 * SLOW / 4; i += 256)
        ((float4*)WhL)[i] = ((const float4*)WhT)[i];
    if (tid < MSG * SLOW / 4) {
        ((float4*)WfL)[tid] = ((const float4*)WfT)[tid];
        ((float4*)WbL)[tid] = ((const float4*)WbT)[tid];
    }

    if (tid < 128) {
        float g = gradP[b * NO1 + no], oh = ohP[b * NO1 + no];
        gsh[tid] = b_lstm[tid] + g * Wi[MSG * 128 + tid] + oh * Wi[(MSG + 1) * 128 + tid];
    }

    int cellA = cl;
    int cellB = cl + 64;
    const float* xfb = xf1T + (size_t)b * 128 * NI1;  // [gate][ni]
    const size_t SS = (size_t)BATCH * NO1 * NI1;
    size_t baseA = ((size_t)b * NO1 + no) * NI1 + cellA;
    size_t baseB = baseA + 64;

    float cA[8], cB[8];
#pragma unroll
    for (int k = 0; k < 8; k++) {
        int s = sgu + 4 * k;
        h_lds[cl * 33 + s] = h1g[(size_t)s * SS + baseA];
        h_lds[(cl + 64) * 33 + s] = h1g[(size_t)s * SS + baseB];
        cA[k] = c1g[(size_t)s * SS + baseA];
        cB[k] = c1g[(size_t)s * SS + baseB];
    }
    __syncthreads();

    float hallA[SLOW], hallB[SLOW];
#pragma unroll
    for (int micro = 0; micro < 2; micro++) {
#pragma unroll
        for (int j = 0; j < SLOW; j++) {
            hallA[j] = h_lds[cl * 33 + j];
            hallB[j] = h_lds[(cl + 64) * 33 + j];
        }
        __syncthreads();
#pragma unroll
        for (int k = 0; k < 8; k++) {
            int s = sgu + 4 * k;
            float g0 = gsh[s], g1 = gsh[SLOW + s], g2 = gsh[2 * SLOW + s], g3 = gsh[3 * SLOW + s];
            float aA0 = g0 + xfb[(s)*NI1 + cellA];
            float aA1 = g1 + xfb[(SLOW + s) * NI1 + cellA];
            float aA2 = g2 + xfb[(2 * SLOW + s) * NI1 + cellA];
            float aA3 = g3 + xfb[(3 * SLOW + s) * NI1 + cellA];
            float aB0 = g0 + xfb[(s)*NI1 + cellB];
            float aB1 = g1 + xfb[(SLOW + s) * NI1 + cellB];
            float aB2 = g2 + xfb[(2 * SLOW + s) * NI1 + cellB];
            float aB3 = g3 + xfb[(3 * SLOW + s) * NI1 + cellB];
#pragma unroll
            for (int j = 0; j < SLOW; j += 4) {
                float4 w0 = *(const float4*)&WhL[(s)*SLOW + j];
                float4 w1 = *(const float4*)&WhL[(SLOW + s) * SLOW + j];
                float4 w2 = *(const float4*)&WhL[(2 * SLOW + s) * SLOW + j];
                float4 w3 = *(const float4*)&WhL[(3 * SLOW + s) * SLOW + j];
                float x0 = hallA[j], x1 = hallA[j + 1], x2 = hallA[j + 2], x3 = hallA[j + 3];
                aA0 += x0 * w0.x + x1 * w0.y + x2 * w0.z + x3 * w0.w;
                aA1 += x0 * w1.x + x1 * w1.y + x2 * w1.z + x3 * w1.w;
                aA2 += x0 * w2.x + x1 * w2.y + x2 * w2.z + x3 * w2.w;
                aA3 += x0 * w3.x + x1 * w3.y + x2 * w3.z + x3 * w3.w;
                float y0 = hallB[j], y1 = hallB[j + 1], y2 = hallB[j + 2], y3 = hallB[j + 3];
                aB0 += y0 * w0.x + y1 * w0.y + y2 * w0.z + y3 * w0.w;
                aB1 += y0 * w1.x + y1 * w1.y + y2 * w1.z + y3 * w1.w;
                aB2 += y0 * w2.x + y1 * w2.y + y2 * w2.z + y3 * w2.w;
                aB3 += y0 * w3.x + y1 * w3.y + y2 * w3.z + y3 * w3.w;
            }
            float cnA = sigf(aA1) * cA[k] + sigf(aA0) * tanh_apx(aA2);
            cA[k] = cnA;
            float hvA = sigf(aA3) * tanh_apx(cnA);
            h_lds[cl * 33 + s] = hvA;
            float cnB = sigf(aB1) * cB[k] + sigf(aB0) * tanh_apx(aB2);
            cB[k] = cnB;
            float hvB = sigf(aB3) * tanh_apx(cnB);
            h_lds[(cl + 64) * 33 + s] = hvB;
            if (micro == 1) {
                h1g[(size_t)s * SS + baseA] = hvA;
                h1g[(size_t)s * SS + baseB] = hvB;
                c1g[(size_t)s * SS + baseA] = cnA;
                c1g[(size_t)s * SS + baseB] = cnB;
            }
        }
        __syncthreads();
    }

#pragma unroll
    for (int j = 0; j < SLOW; j++) {
        hallA[j] = h_lds[cl * 33 + j];
        hallB[j] = h_lds[(cl + 64) * 33 + j];
    }
    __syncthreads();

    float* msgL = h_lds;  // alias
    // ---- fm (need LN'd channel 0) ----
#pragma unroll
    for (int mm = 0; mm < 4; mm++) {
        int m = sgu * 4 + mm;
        float aA = bf[m], aB = aA;
#pragma unroll
        for (int j = 0; j < SLOW; j += 4) {
            float4 w = *(const float4*)&WfL[m * SLOW + j];
            aA += hallA[j] * w.x + hallA[j + 1] * w.y + hallA[j + 2] * w.z + hallA[j + 3] * w.w;
            aB += hallB[j] * w.x + hallB[j + 1] * w.y + hallB[j + 2] * w.z + hallB[j + 3] * w.w;
        }
        msgL[cl * 17 + m] = aA;
        msgL[(cl + 64) * 17 + m] = aB;
    }
    __syncthreads();

    float fm0A, fm0B;
    {
        float fA[MSG], fB[MSG];
#pragma unroll
        for (int m = 0; m < MSG; m++) {
            fA[m] = msgL[cl * 17 + m];
            fB[m] = msgL[(cl + 64) * 17 + m];
        }
        float mA = 0.f, mB = 0.f;
#pragma unroll
        for (int m = 0; m < MSG; m++) { mA += fA[m]; mB += fB[m]; }
        mA *= (1.f / MSG); mB *= (1.f / MSG);
        float vA = 0.f, vB = 0.f;
#pragma unroll
        for (int m = 0; m < MSG; m++) {
            float dA = fA[m] - mA; vA += dA * dA;
            float dB = fB[m] - mB; vB += dB * dB;
        }
        float rA = rsqrtf(vA * (1.f / MSG) + 1e-6f), rB = rsqrtf(vB * (1.f / MSG) + 1e-6f);
        fm0A = (fA[0] - mA) * rA * ln_fs[0] + ln_fb[0];
        fm0B = (fB[0] - mB) * rB * ln_fs[0] + ln_fb[0];
    }
    __syncthreads();  // fm reads done before bm overwrites

    // ---- bm ----
#pragma unroll
    for (int mm = 0; mm < 4; mm++) {
        int m = sgu * 4 + mm;
        float aA = bwb[m], aB = aA;
#pragma unroll
        for (int j = 0; j < SLOW; j += 4) {
            float4 w = *(const float4*)&WbL[m * SLOW + j];
            aA += hallA[j] * w.x + hallA[j + 1] * w.y + hallA[j + 2] * w.z + hallA[j + 3] * w.w;
            aB += hallB[j] * w.x + hallB[j + 1] * w.y + hallB[j + 2] * w.z + hallB[j + 3] * w.w;
        }
        msgL[cl * 17 + m] = aA;
        msgL[(cl + 64) * 17 + m] = aB;
    }
    __syncthreads();
    {
        float fA[MSG], fB[MSG];
#pragma unroll
        for (int m = 0; m < MSG; m++) {
            fA[m] = msgL[cl * 17 + m];
            fB[m] = msgL[(cl + 64) * 17 + m];
        }
        float mA = 0.f, mB = 0.f;
#pragma unroll
        for (int m = 0; m < MSG; m++) { mA += fA[m]; mB += fB[m]; }
        mA *= (1.f / MSG); mB *= (1.f / MSG);
        float vA = 0.f, vB = 0.f;
#pragma unroll
        for (int m = 0; m < MSG; m++) {
            float dA = fA[m] - mA; vA += dA * dA;
            float dB = fB[m] - mB; vB += dB * dB;
        }
        float rA = rsqrtf(vA * (1.f / MSG) + 1e-6f), rB = rsqrtf(vB * (1.f / MSG) + 1e-6f);
#pragma unroll
        for (int mm = 0; mm < 4; mm++) {
            int m = sgu * 4 + mm;
            float sc = ln_bs[m], bb = ln_bb[m];
            bm_g[(((size_t)b * NO1 + no) * MSG + m) * NI1 + cellA] = (fA[m] - mA) * rA * sc + bb;
            bm_g[(((size_t)b * NO1 + no) * MSG + m) * NI1 + cellB] = (fB[m] - mB) * rB * sc + bb;
        }
    }

    // outsum: each cell counted 4x (per s-group) -> /512
    int lane = tid & 63, wv = tid >> 6;
    float x = fm0A + fm0B;
#pragma unroll
    for (int d = 1; d < 64; d <<= 1) x += __shfl_xor(x, d);
    if (lane == 0) red[wv] = x;
    __syncthreads();
    if (tid == 0)
        outsum[b * NO1 + no] = (red[0] + red[1] + red[2] + red[3]) * (1.f / 512.f);
}

// ---------------------------------------------------------------------------
// nb1[b,ni,m] = mean over no of bm_g
// ---------------------------------------------------------------------------
__global__ void k_red1(const float* __restrict__ bm_g, float* __restrict__ nb1) {
    int g = blockIdx.x * 256 + threadIdx.x;  // < 8*128*16 = 16384
    int ni = g & 127;
    int m = (g >> 7) & 15;
    int b = g >> 11;
    float a = 0.f;
#pragma unroll 8
    for (int no = 0; no < NO1; no++)
        a += bm_g[(((size_t)b * NO1 + no) * MSG + m) * NI1 + ni];
    nb1[((size_t)b * NI1 + ni) * MSG + m] = a * (1.f / NO1);
}

// ---------------------------------------------------------------------------
// out/softmax/error: block per b (64 threads = classes)
// ---------------------------------------------------------------------------
__global__ void k_out(const float* __restrict__ outsum, const int* __restrict__ labels,
                      float* __restrict__ dout, float* __restrict__ gradP,
                      float* __restrict__ ohP, int t) {
    int b = blockIdx.x;
    int no = threadIdx.x;
    float v = outsum[b * NO1 + no];
    float mx = v;
#pragma unroll
    for (int d = 1; d < 64; d <<= 1) mx = fmaxf(mx, __shfl_xor(mx, d));
    float e = __expf(v - mx);
    float sum = e;
#pragma unroll
    for (int d = 1; d < 64; d <<= 1) sum += __shfl_xor(sum, d);
    int lbl = labels[t * BATCH + b];
    float oh = (no == lbl) ? 1.f : 0.f;
    gradP[b * NO1 + no] = e / sum - oh;
    ohP[b * NO1 + no] = oh;
    dout[((size_t)t * BATCH + b) * NO1 + no] = v;
}

// ---------------------------------------------------------------------------

extern "C" void kernel_launch(void* const* d_in, const int* in_sizes, int n_in,
                              void* d_out, int out_size, void* d_ws, size_t ws_size,
                              hipStream_t stream) {
    const float* inp   = (const float*)d_in[0];
    const int*   labels= (const int*)d_in[1];
    const float* Wi    = (const float*)d_in[2];
    const float* Wh    = (const float*)d_in[3];
    const float* b_lstm= (const float*)d_in[4];
    const float* Wf    = (const float*)d_in[5];
    const float* bf    = (const float*)d_in[6];
    const float* Wb    = (const float*)d_in[7];
    const float* bwb   = (const float*)d_in[8];
    const float* ln_fs = (const float*)d_in[9];
    const float* ln_fb = (const float*)d_in[10];
    const float* ln_bs = (const float*)d_in[11];
    const float* ln_bb = (const float*)d_in[12];
    float* out = (float*)d_out;

    float* w = (float*)d_ws;
    const size_t SZ_H0 = (size_t)SLOW * BATCH * NO0 * NI0;  // 8,388,608
    const size_t SZ_H1 = (size_t)SLOW * BATCH * NO1 * NI1;  // 2,097,152
    float* h0   = w;
    float* c0   = h0 + SZ_H0;
    float* h1   = c0 + SZ_H0;
    float* c1   = h1 + SZ_H1;
    float* xf1T = c1 + SZ_H1;                                 // 8*128*128
    float* bm_g = xf1T + (size_t)BATCH * 128 * NO0;           // 8*64*16*128
    float* nb1  = bm_g + (size_t)BATCH * NO1 * MSG * NI1;     // 8*128*16
    float* nf_part = nb1 + (size_t)BATCH * NI1 * MSG;         // 8*128*2*16
    float* outsum = nf_part + (size_t)BATCH * NO0 * 2 * MSG;  // 512
    float* gradP  = outsum + BATCH * NO1;                     // 512
    float* ohP    = gradP + BATCH * NO1;                      // 512
    float* WhT    = ohP + BATCH * NO1;                        // 128*32
    float* WfT    = WhT + 128 * SLOW;                         // 16*32
    float* WbT    = WfT + MSG * SLOW;                         // 16*32
    size_t total_floats = (size_t)(WbT - w) + MSG * SLOW;

    hipMemsetAsync(d_ws, 0, total_floats * sizeof(float), stream);
    k_prep<<<16, 256, 0, stream>>>(Wh, Wf, Wb, WhT, WfT, WbT);

    for (int t = 0; t < TSTEPS; t++) {
        if (t) k_merge<<<2560, 256, 0, stream>>>(h0, c0, h1, c1);
        k_l0<<<BATCH * NO0 * 2, 256, 0, stream>>>(inp, Wi, WhT, b_lstm, WfT, bf, ln_fs, ln_fb,
                                                  h0, c0, nb1, nf_part, t);
        k_xf<<<BATCH * 128, 128, 0, stream>>>(nf_part, Wi, xf1T);
        k_l1<<<BATCH * NO1, 256, 0, stream>>>(Wi, WhT, b_lstm, WfT, bf, ln_fs, ln_fb,
                                              WbT, bwb, ln_bs, ln_bb,
                                              h1, c1, xf1T, gradP, ohP, bm_g, outsum);
        k_red1<<<64, 256, 0, stream>>>(bm_g, nb1);
        k_out<<<BATCH, NO1, 0, stream>>>(outsum, labels, out, gradP, ohP, t);
    }
}

// Round 7
// 723.315 us; speedup vs baseline: 1.2642x; 1.2642x over previous
//
#include <hip/hip_runtime.h>
#include <hip/hip_bf16.h>

#define SLOW 32
#define MSG 16
#define TSTEPS 4
#define BATCH 8
#define NI0 256
#define NO0 128
#define NI1 128
#define NO1 64

__device__ __forceinline__ float rcpf(float x) { return __builtin_amdgcn_rcpf(x); }
__device__ __forceinline__ float sigf(float x) { return rcpf(1.f + __expf(-x)); }
__device__ __forceinline__ float tanh_apx(float x) {
    float xc = fminf(fmaxf(x, -15.f), 15.f);
    float e = __expf(-2.f * xc);
    return (1.f - e) * rcpf(1.f + e);
}

// ---------------------------------------------------------------------------
// prep: transpose Wh (32x128) -> WhT (128x32), Wf/Wb (32x16) -> WfT/WbT (16x32)
// ---------------------------------------------------------------------------
__global__ void k_prep(const float* __restrict__ Wh, const float* __restrict__ Wf,
                       const float* __restrict__ Wb,
                       float* __restrict__ WhT, float* __restrict__ WfT,
                       float* __restrict__ WbT) {
    int i = blockIdx.x * 256 + threadIdx.x;
    if (i < 128 * SLOW) {
        int j = i >> 7, k = i & 127;
        WhT[k * SLOW + j] = Wh[i];
    }
    if (i < MSG * SLOW) {
        int j = i >> 4, m = i & 15;
        WfT[m * SLOW + j] = Wf[i];
        WbT[m * SLOW + j] = Wb[i];
    }
}

// ---------------------------------------------------------------------------
// merge: for slow channels s<16, replace h/c with mean over batch (in place)
// ---------------------------------------------------------------------------
__global__ void k_merge(float* __restrict__ h0, float* __restrict__ c0,
                        float* __restrict__ h1, float* __restrict__ c1) {
    int idx = blockIdx.x * blockDim.x + threadIdx.x;
    const int P0 = NO0 * NI0;
    const int P1 = NO1 * NI1;
    const int N0 = 16 * P0;
    const int N1 = 16 * P1;
    float* h; float* c; int s, p, plane;
    if (idx < N0) { h = h0; c = c0; s = idx / P0; p = idx % P0; plane = P0; }
    else {
        idx -= N0;
        if (idx >= N1) return;
        h = h1; c = c1; s = idx / P1; p = idx % P1; plane = P1;
    }
    size_t base = (size_t)(s * BATCH) * plane + p;
    float sh = 0.f, sc = 0.f;
#pragma unroll
    for (int b = 0; b < BATCH; b++) { sh += h[base + (size_t)b * plane]; sc += c[base + (size_t)b * plane]; }
    sh *= 0.125f; sc *= 0.125f;
#pragma unroll
    for (int b = 0; b < BATCH; b++) { h[base + (size_t)b * plane] = sh; c[base + (size_t)b * plane] = sc; }
}

// ---------------------------------------------------------------------------
// Layer 0: block = (b,no,half), 256 threads = 4 s-groups x 64 lanes,
// each thread handles 2 cells (cl and cl+64) -> 128 cells/block.
// ---------------------------------------------------------------------------
__global__ __launch_bounds__(256) void k_l0(
    const float* __restrict__ inp, const float* __restrict__ Wi,
    const float* __restrict__ WhT, const float* __restrict__ b_lstm,
    const float* __restrict__ WfT, const float* __restrict__ bf,
    const float* __restrict__ ln_fs, const float* __restrict__ ln_fb,
    float* __restrict__ h0g, float* __restrict__ c0g,
    const float* __restrict__ nb1, float* __restrict__ nf_part, int t) {
    int q = blockIdx.x & 1;
    int no = (blockIdx.x >> 1) & 127;
    int b = blockIdx.x >> 8;
    int tid = threadIdx.x;
    int cl = tid & 63;
    int sgu = __builtin_amdgcn_readfirstlane(tid >> 6);  // 0..3, wave-uniform

    __shared__ __align__(16) float WhL[128 * SLOW];   // 16 KB
    __shared__ __align__(16) float WfL[MSG * SLOW];   // 2 KB
    __shared__ float h_lds[128 * 33];                 // fm exchange aliases this
    __shared__ float gsh[128];
    __shared__ float red[4][MSG];

#pragma unroll
    for (int i = tid; i < 128 * SLOW / 4; i += 256)
        ((float4*)WhL)[i] = ((const float4*)WhT)[i];
    if (tid < MSG * SLOW / 4)
        ((float4*)WfL)[tid] = ((const float4*)WfT)[tid];

    if (tid < 128) {
        float acc = b_lstm[tid];
        const float* nbr = nb1 + ((size_t)b * NO0 + no) * MSG;
#pragma unroll
        for (int m = 0; m < MSG; m++) acc += nbr[m] * Wi[(MSG + m) * 128 + tid];
        gsh[tid] = acc;
    }

    int cellA = q * 128 + cl;
    int cellB = cellA + 64;
    float miA = inp[((size_t)t * BATCH + b) * NI0 + cellA];
    float miB = inp[((size_t)t * BATCH + b) * NI0 + cellB];
    const size_t SS = (size_t)BATCH * NO0 * NI0;
    size_t baseA = ((size_t)b * NO0 + no) * NI0 + cellA;
    size_t baseB = baseA + 64;

    float cA[8], cB[8];
#pragma unroll
    for (int k = 0; k < 8; k++) {
        int s = sgu + 4 * k;
        h_lds[cl * 33 + s] = h0g[(size_t)s * SS + baseA];
        h_lds[(cl + 64) * 33 + s] = h0g[(size_t)s * SS + baseB];
        cA[k] = c0g[(size_t)s * SS + baseA];
        cB[k] = c0g[(size_t)s * SS + baseB];
    }
    __syncthreads();

    float hallA[SLOW], hallB[SLOW];
#pragma unroll
    for (int micro = 0; micro < 2; micro++) {
#pragma unroll
        for (int j = 0; j < SLOW; j++) {
            hallA[j] = h_lds[cl * 33 + j];
            hallB[j] = h_lds[(cl + 64) * 33 + j];
        }
        __syncthreads();
#pragma unroll
        for (int k = 0; k < 8; k++) {
            int s = sgu + 4 * k;
            float g0 = gsh[s], g1 = gsh[SLOW + s], g2 = gsh[2 * SLOW + s], g3 = gsh[3 * SLOW + s];
            float wi0 = Wi[s], wi1 = Wi[SLOW + s], wi2 = Wi[2 * SLOW + s], wi3 = Wi[3 * SLOW + s];
            float aA0 = g0 + miA * wi0, aA1 = g1 + miA * wi1, aA2 = g2 + miA * wi2, aA3 = g3 + miA * wi3;
            float aB0 = g0 + miB * wi0, aB1 = g1 + miB * wi1, aB2 = g2 + miB * wi2, aB3 = g3 + miB * wi3;
#pragma unroll
            for (int j = 0; j < SLOW; j += 4) {
                float4 w0 = *(const float4*)&WhL[(s)*SLOW + j];
                float4 w1 = *(const float4*)&WhL[(SLOW + s) * SLOW + j];
                float4 w2 = *(const float4*)&WhL[(2 * SLOW + s) * SLOW + j];
                float4 w3 = *(const float4*)&WhL[(3 * SLOW + s) * SLOW + j];
                float x0 = hallA[j], x1 = hallA[j + 1], x2 = hallA[j + 2], x3 = hallA[j + 3];
                aA0 += x0 * w0.x + x1 * w0.y + x2 * w0.z + x3 * w0.w;
                aA1 += x0 * w1.x + x1 * w1.y + x2 * w1.z + x3 * w1.w;
                aA2 += x0 * w2.x + x1 * w2.y + x2 * w2.z + x3 * w2.w;
                aA3 += x0 * w3.x + x1 * w3.y + x2 * w3.z + x3 * w3.w;
                float y0 = hallB[j], y1 = hallB[j + 1], y2 = hallB[j + 2], y3 = hallB[j + 3];
                aB0 += y0 * w0.x + y1 * w0.y + y2 * w0.z + y3 * w0.w;
                aB1 += y0 * w1.x + y1 * w1.y + y2 * w1.z + y3 * w1.w;
                aB2 += y0 * w2.x + y1 * w2.y + y2 * w2.z + y3 * w2.w;
                aB3 += y0 * w3.x + y1 * w3.y + y2 * w3.z + y3 * w3.w;
            }
            float cnA = sigf(aA1) * cA[k] + sigf(aA0) * tanh_apx(aA2);
            cA[k] = cnA;
            float hvA = sigf(aA3) * tanh_apx(cnA);
            h_lds[cl * 33 + s] = hvA;
            float cnB = sigf(aB1) * cB[k] + sigf(aB0) * tanh_apx(aB2);
            cB[k] = cnB;
            float hvB = sigf(aB3) * tanh_apx(cnB);
            h_lds[(cl + 64) * 33 + s] = hvB;
            if (micro == 1) {
                h0g[(size_t)s * SS + baseA] = hvA;
                h0g[(size_t)s * SS + baseB] = hvB;
                c0g[(size_t)s * SS + baseA] = cnA;
                c0g[(size_t)s * SS + baseB] = cnB;
            }
        }
        __syncthreads();
    }

#pragma unroll
    for (int j = 0; j < SLOW; j++) {
        hallA[j] = h_lds[cl * 33 + j];
        hallB[j] = h_lds[(cl + 64) * 33 + j];
    }
    __syncthreads();  // all hall reads done before alias overwrite

    float* fmL = h_lds;  // alias: 128*17 <= 128*33
#pragma unroll
    for (int mm = 0; mm < 4; mm++) {
        int m = sgu * 4 + mm;
        float aA = bf[m], aB = aA;
#pragma unroll
        for (int j = 0; j < SLOW; j += 4) {
            float4 w = *(const float4*)&WfL[m * SLOW + j];
            aA += hallA[j] * w.x + hallA[j + 1] * w.y + hallA[j + 2] * w.z + hallA[j + 3] * w.w;
            aB += hallB[j] * w.x + hallB[j + 1] * w.y + hallB[j + 2] * w.z + hallB[j + 3] * w.w;
        }
        fmL[cl * 17 + m] = aA;
        fmL[(cl + 64) * 17 + m] = aB;
    }
    __syncthreads();

    float v[MSG];
    {
        float fmA[MSG], fmB[MSG];
#pragma unroll
        for (int m = 0; m < MSG; m++) {
            fmA[m] = fmL[cl * 17 + m];
            fmB[m] = fmL[(cl + 64) * 17 + m];
        }
        float meanA = 0.f, meanB = 0.f;
#pragma unroll
        for (int m = 0; m < MSG; m++) { meanA += fmA[m]; meanB += fmB[m]; }
        meanA *= (1.f / MSG); meanB *= (1.f / MSG);
        float varA = 0.f, varB = 0.f;
#pragma unroll
        for (int m = 0; m < MSG; m++) {
            float dA = fmA[m] - meanA; varA += dA * dA;
            float dB = fmB[m] - meanB; varB += dB * dB;
        }
        varA *= (1.f / MSG); varB *= (1.f / MSG);
        float rsA = rsqrtf(varA + 1e-6f), rsB = rsqrtf(varB + 1e-6f);
#pragma unroll
        for (int m = 0; m < MSG; m++) {
            float s = ln_fs[m], bb = ln_fb[m];
            v[m] = ((fmA[m] - meanA) * rsA + (fmB[m] - meanB) * rsB) * s + 2.f * bb;
        }
    }

    int lane = tid & 63, wv = tid >> 6;
#pragma unroll
    for (int m = 0; m < MSG; m++) {
        float x = v[m];
#pragma unroll
        for (int d = 1; d < 64; d <<= 1) x += __shfl_xor(x, d);
        if (lane == 0) red[wv][m] = x;
    }
    __syncthreads();
    if (tid < MSG) {
        float a = red[0][tid] + red[1][tid] + red[2][tid] + red[3][tid];
        nf_part[(((size_t)b * NO0 + no) * 2 + q) * MSG + tid] = a;
    }
}

// ---------------------------------------------------------------------------
// k_xf: xf1T[b][k][no0] = sum_m nf[b,no0,m] * Wi[m,k], nf = sum of 2 parts /1024
// ---------------------------------------------------------------------------
__global__ __launch_bounds__(128) void k_xf(const float* __restrict__ nf_part,
                                            const float* __restrict__ Wi,
                                            float* __restrict__ xf1T) {
    int b = blockIdx.x >> 7;
    int k = blockIdx.x & 127;
    int no = threadIdx.x;
    float nf[MSG];
#pragma unroll
    for (int m = 0; m < MSG; m++) nf[m] = 0.f;
    const float* p = nf_part + ((size_t)b * NO0 + no) * 2 * MSG;
#pragma unroll
    for (int qm = 0; qm < 2 * MSG; qm++) nf[qm & 15] += p[qm];
    float a = 0.f;
#pragma unroll
    for (int m = 0; m < MSG; m++) a += nf[m] * Wi[m * 128 + k];
    xf1T[((size_t)b * 128 + k) * NO0 + no] = a * (1.f / 1024.f);
}

// ---------------------------------------------------------------------------
// Layer 1 (round-5 structure): block = (b,no,half), 256 threads =
// 4 s-groups x 64 cells, xf gate terms preloaded into registers.
// ---------------------------------------------------------------------------
__global__ __launch_bounds__(256) void k_l1(
    const float* __restrict__ Wi, const float* __restrict__ WhT,
    const float* __restrict__ b_lstm,
    const float* __restrict__ WfT, const float* __restrict__ bf,
    const float* __restrict__ ln_fs, const float* __restrict__ ln_fb,
    const float* __restrict__ WbT, const float* __restrict__ bwb,
    const float* __restrict__ ln_bs, const float* __restrict__ ln_bb,
    float* __restrict__ h1g, float* __restrict__ c1g,
    const float* __restrict__ xf1T, const float* __restrict__ gradP,
    const float* __restrict__ ohP,
    float* __restrict__ bm_g, float* __restrict__ outsum_part) {
    int q = blockIdx.x & 1;
    int no = (blockIdx.x >> 1) & 63;
    int b = blockIdx.x >> 7;
    int tid = threadIdx.x;
    int cl = tid & 63;
    int sgu = __builtin_amdgcn_readfirstlane(tid >> 6);
    int cell = q * 64 + cl;

    __shared__ __align__(16) float WhL[128 * SLOW];
    __shared__ __align__(16) float WfL[MSG * SLOW];
    __shared__ __align__(16) float WbL[MSG * SLOW];
    __shared__ float h_lds[64 * 33];
    __shared__ float msg_lds[64 * 17];
    __shared__ float gsh[128];
    __shared__ float red[4];

#pragma unroll
    for (int i = tid; i < 128 * SLOW / 4; i += 256)
        ((float4*)WhL)[i] = ((const float4*)WhT)[i];
    if (tid < MSG * SLOW / 4) {
        ((float4*)WfL)[tid] = ((const float4*)WfT)[tid];
        ((float4*)WbL)[tid] = ((const float4*)WbT)[tid];
    }

    if (tid < 128) {
        float g = gradP[b * NO1 + no], oh = ohP[b * NO1 + no];
        gsh[tid] = b_lstm[tid] + g * Wi[MSG * 128 + tid] + oh * Wi[(MSG + 1) * 128 + tid];
    }

    const float* xfb = xf1T + (size_t)b * 128 * NI1;  // [gate][ni]
    const size_t SS = (size_t)BATCH * NO1 * NI1;
    size_t base = ((size_t)b * NO1 + no) * NI1 + cell;

    float xf0[8], xf1[8], xf2[8], xf3[8];
#pragma unroll
    for (int k = 0; k < 8; k++) {
        int s = sgu + 4 * k;
        xf0[k] = xfb[s * NI1 + cell];
        xf1[k] = xfb[(SLOW + s) * NI1 + cell];
        xf2[k] = xfb[(2 * SLOW + s) * NI1 + cell];
        xf3[k] = xfb[(3 * SLOW + s) * NI1 + cell];
    }

    float c[8], hcur[8];
#pragma unroll
    for (int k = 0; k < 8; k++) {
        int s = sgu + 4 * k;
        hcur[k] = h1g[(size_t)s * SS + base];
        c[k] = c1g[(size_t)s * SS + base];
        h_lds[cl * 33 + s] = hcur[k];
    }
    __syncthreads();

    float hall[SLOW];
#pragma unroll
    for (int micro = 0; micro < 2; micro++) {
#pragma unroll
        for (int j = 0; j < SLOW; j++) hall[j] = h_lds[cl * 33 + j];
        __syncthreads();
#pragma unroll
        for (int k = 0; k < 8; k++) {
            int s = sgu + 4 * k;
            float a0 = gsh[s] + xf0[k];
            float a1 = gsh[SLOW + s] + xf1[k];
            float a2 = gsh[2 * SLOW + s] + xf2[k];
            float a3 = gsh[3 * SLOW + s] + xf3[k];
#pragma unroll
            for (int j = 0; j < SLOW; j += 4) {
                float4 w0 = *(const float4*)&WhL[(s)*SLOW + j];
                float4 w1 = *(const float4*)&WhL[(SLOW + s) * SLOW + j];
                float4 w2 = *(const float4*)&WhL[(2 * SLOW + s) * SLOW + j];
                float4 w3 = *(const float4*)&WhL[(3 * SLOW + s) * SLOW + j];
                float x0 = hall[j], x1 = hall[j + 1], x2 = hall[j + 2], x3 = hall[j + 3];
                a0 += x0 * w0.x + x1 * w0.y + x2 * w0.z + x3 * w0.w;
                a1 += x0 * w1.x + x1 * w1.y + x2 * w1.z + x3 * w1.w;
                a2 += x0 * w2.x + x1 * w2.y + x2 * w2.z + x3 * w2.w;
                a3 += x0 * w3.x + x1 * w3.y + x2 * w3.z + x3 * w3.w;
            }
            float cn = sigf(a1) * c[k] + sigf(a0) * tanh_apx(a2);
            c[k] = cn;
            float hv = sigf(a3) * tanh_apx(cn);
            hcur[k] = hv;
            h_lds[cl * 33 + s] = hv;
        }
        __syncthreads();
    }

#pragma unroll
    for (int j = 0; j < SLOW; j++) hall[j] = h_lds[cl * 33 + j];

    // ---- fm (need LN'd channel 0) ----
#pragma unroll
    for (int mm = 0; mm < 4; mm++) {
        int m = sgu * 4 + mm;
        float a = bf[m];
#pragma unroll
        for (int j = 0; j < SLOW; j += 4) {
            float4 w = *(const float4*)&WfL[m * SLOW + j];
            a += hall[j] * w.x + hall[j + 1] * w.y + hall[j + 2] * w.z + hall[j + 3] * w.w;
        }
        msg_lds[cl * 17 + m] = a;
    }

    // state writeback
#pragma unroll
    for (int k = 0; k < 8; k++) {
        int s = sgu + 4 * k;
        h1g[(size_t)s * SS + base] = hcur[k];
        c1g[(size_t)s * SS + base] = c[k];
    }
    __syncthreads();

    float fm0;
    {
        float fmv[MSG];
#pragma unroll
        for (int m = 0; m < MSG; m++) fmv[m] = msg_lds[cl * 17 + m];
        float mean = 0.f;
#pragma unroll
        for (int m = 0; m < MSG; m++) mean += fmv[m];
        mean *= (1.f / MSG);
        float var = 0.f;
#pragma unroll
        for (int m = 0; m < MSG; m++) { float d = fmv[m] - mean; var += d * d; }
        var *= (1.f / MSG);
        float rs = rsqrtf(var + 1e-6f);
        fm0 = (fmv[0] - mean) * rs * ln_fs[0] + ln_fb[0];
    }
    __syncthreads();  // msg_lds reads done before bm overwrites

    // ---- bm ----
#pragma unroll
    for (int mm = 0; mm < 4; mm++) {
        int m = sgu * 4 + mm;
        float a = bwb[m];
#pragma unroll
        for (int j = 0; j < SLOW; j += 4) {
            float4 w = *(const float4*)&WbL[m * SLOW + j];
            a += hall[j] * w.x + hall[j + 1] * w.y + hall[j + 2] * w.z + hall[j + 3] * w.w;
        }
        msg_lds[cl * 17 + m] = a;
    }
    __syncthreads();
    {
        float bmv[MSG];
#pragma unroll
        for (int m = 0; m < MSG; m++) bmv[m] = msg_lds[cl * 17 + m];
        float mean = 0.f;
#pragma unroll
        for (int m = 0; m < MSG; m++) mean += bmv[m];
        mean *= (1.f / MSG);
        float var = 0.f;
#pragma unroll
        for (int m = 0; m < MSG; m++) { float d = bmv[m] - mean; var += d * d; }
        var *= (1.f / MSG);
        float rs = rsqrtf(var + 1e-6f);
#pragma unroll
        for (int m = 0; m < MSG; m++) bmv[m] = (bmv[m] - mean) * rs * ln_bs[m] + ln_bb[m];
#pragma unroll
        for (int mm = 0; mm < 4; mm++) {
            int m = sgu * 4 + mm;
            bm_g[(((size_t)b * NO1 + no) * MSG + m) * NI1 + cell] = bmv[m];
        }
    }

    // raw partial sum of fm0 over block (each cell counted 4x)
    int lane = tid & 63, wv = tid >> 6;
    float v = fm0;
#pragma unroll
    for (int d = 1; d < 64; d <<= 1) v += __shfl_xor(v, d);
    if (lane == 0) red[wv] = v;
    __syncthreads();
    if (tid == 0)
        outsum_part[((size_t)b * NO1 + no) * 2 + q] = red[0] + red[1] + red[2] + red[3];
}

// ---------------------------------------------------------------------------
// nb1[b,ni,m] = mean over no of bm_g
// ---------------------------------------------------------------------------
__global__ void k_red1(const float* __restrict__ bm_g, float* __restrict__ nb1) {
    int g = blockIdx.x * 256 + threadIdx.x;  // < 8*128*16 = 16384
    int ni = g & 127;
    int m = (g >> 7) & 15;
    int b = g >> 11;
    float a = 0.f;
#pragma unroll 8
    for (int no = 0; no < NO1; no++)
        a += bm_g[(((size_t)b * NO1 + no) * MSG + m) * NI1 + ni];
    nb1[((size_t)b * NI1 + ni) * MSG + m] = a * (1.f / NO1);
}

// ---------------------------------------------------------------------------
// out/softmax/error: block per b (64 threads = classes)
// ---------------------------------------------------------------------------
__global__ void k_out(const float* __restrict__ outsum_part, const int* __restrict__ labels,
                      float* __restrict__ dout, float* __restrict__ gradP,
                      float* __restrict__ ohP, int t) {
    int b = blockIdx.x;
    int no = threadIdx.x;
    float v = (outsum_part[((size_t)b * NO1 + no) * 2] +
               outsum_part[((size_t)b * NO1 + no) * 2 + 1]) * (1.f / 512.f);
    float mx = v;
#pragma unroll
    for (int d = 1; d < 64; d <<= 1) mx = fmaxf(mx, __shfl_xor(mx, d));
    float e = __expf(v - mx);
    float sum = e;
#pragma unroll
    for (int d = 1; d < 64; d <<= 1) sum += __shfl_xor(sum, d);
    int lbl = labels[t * BATCH + b];
    float oh = (no == lbl) ? 1.f : 0.f;
    gradP[b * NO1 + no] = e / sum - oh;
    ohP[b * NO1 + no] = oh;
    dout[((size_t)t * BATCH + b) * NO1 + no] = v;
}

// ---------------------------------------------------------------------------

extern "C" void kernel_launch(void* const* d_in, const int* in_sizes, int n_in,
                              void* d_out, int out_size, void* d_ws, size_t ws_size,
                              hipStream_t stream) {
    const float* inp   = (const float*)d_in[0];
    const int*   labels= (const int*)d_in[1];
    const float* Wi    = (const float*)d_in[2];
    const float* Wh    = (const float*)d_in[3];
    const float* b_lstm= (const float*)d_in[4];
    const float* Wf    = (const float*)d_in[5];
    const float* bf    = (const float*)d_in[6];
    const float* Wb    = (const float*)d_in[7];
    const float* bwb   = (const float*)d_in[8];
    const float* ln_fs = (const float*)d_in[9];
    const float* ln_fb = (const float*)d_in[10];
    const float* ln_bs = (const float*)d_in[11];
    const float* ln_bb = (const float*)d_in[12];
    float* out = (float*)d_out;

    float* w = (float*)d_ws;
    const size_t SZ_H0 = (size_t)SLOW * BATCH * NO0 * NI0;  // 8,388,608
    const size_t SZ_H1 = (size_t)SLOW * BATCH * NO1 * NI1;  // 2,097,152
    float* h0   = w;
    float* c0   = h0 + SZ_H0;
    float* h1   = c0 + SZ_H0;
    float* c1   = h1 + SZ_H1;
    float* xf1T = c1 + SZ_H1;                                 // 8*128*128
    float* bm_g = xf1T + (size_t)BATCH * 128 * NO0;           // 8*64*16*128
    float* nb1  = bm_g + (size_t)BATCH * NO1 * MSG * NI1;     // 8*128*16
    float* nf_part = nb1 + (size_t)BATCH * NI1 * MSG;         // 8*128*2*16
    float* outsum_part = nf_part + (size_t)BATCH * NO0 * 2 * MSG;  // 8*64*2
    float* gradP  = outsum_part + BATCH * NO1 * 2;            // 512
    float* ohP    = gradP + BATCH * NO1;                      // 512
    float* WhT    = ohP + BATCH * NO1;                        // 128*32
    float* WfT    = WhT + 128 * SLOW;                         // 16*32
    float* WbT    = WfT + MSG * SLOW;                         // 16*32
    size_t total_floats = (size_t)(WbT - w) + MSG * SLOW;

    hipMemsetAsync(d_ws, 0, total_floats * sizeof(float), stream);
    k_prep<<<16, 256, 0, stream>>>(Wh, Wf, Wb, WhT, WfT, WbT);

    for (int t = 0; t < TSTEPS; t++) {
        if (t) k_merge<<<2560, 256, 0, stream>>>(h0, c0, h1, c1);
        k_l0<<<BATCH * NO0 * 2, 256, 0, stream>>>(inp, Wi, WhT, b_lstm, WfT, bf, ln_fs, ln_fb,
                                                  h0, c0, nb1, nf_part, t);
        k_xf<<<BATCH * 128, 128, 0, stream>>>(nf_part, Wi, xf1T);
        k_l1<<<BATCH * NO1 * 2, 256, 0, stream>>>(Wi, WhT, b_lstm, WfT, bf, ln_fs, ln_fb,
                                                  WbT, bwb, ln_bs, ln_bb,
                                                  h1, c1, xf1T, gradP, ohP, bm_g, outsum_part);
        k_red1<<<64, 256, 0, stream>>>(bm_g, nb1);
        k_out<<<BATCH, NO1, 0, stream>>>(outsum_part, labels, out, gradP, ohP, t);
    }
}

// Round 9
// 419.149 us; speedup vs baseline: 2.1816x; 1.7257x over previous
//
#include <hip/hip_runtime.h>
#include <hip/hip_bf16.h>

#define SLOW 32
#define MSG 16
#define TSTEPS 4
#define BATCH 8
#define NI0 256
#define NO0 128
#define NI1 128
#define NO1 64

typedef __bf16 bf16x8 __attribute__((ext_vector_type(8)));
typedef float f32x4 __attribute__((ext_vector_type(4)));

__device__ __forceinline__ float rcpf(float x) { return __builtin_amdgcn_rcpf(x); }
__device__ __forceinline__ float sigf(float x) { return rcpf(1.f + __expf(-x)); }
__device__ __forceinline__ float tanh_apx(float x) {
    float xc = fminf(fmaxf(x, -15.f), 15.f);
    float e = __expf(-2.f * xc);
    return (1.f - e) * rcpf(1.f + e);
}
__device__ __forceinline__ unsigned short f2bf(float x) {
    __bf16 h = (__bf16)x;
    return __builtin_bit_cast(unsigned short, h);
}
__device__ __forceinline__ float bf2f(unsigned short u) {
    __bf16 h = __builtin_bit_cast(__bf16, u);
    return (float)h;
}
__device__ __forceinline__ float sum16(float v) {
    v += __shfl_xor(v, 1); v += __shfl_xor(v, 2);
    v += __shfl_xor(v, 4); v += __shfl_xor(v, 8);
    return v;
}

// ---------------------------------------------------------------------------
// k_prep: pack B-fragments (bf16) for Wh (8 n-tiles), Wf, Wb.
// frag slot (lane l, elem e) = W[k = (l>>4)*8 + e][col = nt*16 + (l&15)]
// (k-slot bijection arbitrary but IDENTICAL for A and B -> contraction exact)
// ---------------------------------------------------------------------------
__global__ void k_prep(const float* __restrict__ Wh, const float* __restrict__ Wf,
                       const float* __restrict__ Wb,
                       unsigned short* __restrict__ WhBp,
                       unsigned short* __restrict__ WfBp,
                       unsigned short* __restrict__ WbBp) {
    int i = blockIdx.x * 256 + threadIdx.x;
    if (i < 4096) {
        int e = i & 7, l = (i >> 3) & 63, nt = i >> 9;
        int k = (l >> 4) * 8 + e, col = nt * 16 + (l & 15);
        WhBp[i] = f2bf(Wh[k * 128 + col]);
    } else if (i < 4608) {
        int j = i - 4096;
        int e = j & 7, l = j >> 3;
        int k = (l >> 4) * 8 + e;
        WfBp[j] = f2bf(Wf[k * 16 + (l & 15)]);
    } else if (i < 5120) {
        int j = i - 4608;
        int e = j & 7, l = j >> 3;
        int k = (l >> 4) * 8 + e;
        WbBp[j] = f2bf(Wb[k * 16 + (l & 15)]);
    }
}

// ---------------------------------------------------------------------------
// merge: mean over batch for slow channels s<16.
// layouts: h bf16 [b][no][cell][32], c f32 [b][no][cell][32]
// ---------------------------------------------------------------------------
__global__ void k_merge(unsigned int* __restrict__ h0, float* __restrict__ c0,
                        unsigned int* __restrict__ h1, float* __restrict__ c1) {
    int idx = blockIdx.x * 256 + threadIdx.x;
    if (idx < 262144) {  // l0 h: u32 pairs over first 16 s
        int u = idx & 7, cell = (idx >> 3) & 255, no = idx >> 11;
        size_t base = ((size_t)no * 256 + cell) * 16 + u;
        const size_t strd = (size_t)128 * 256 * 16;
        float s0 = 0.f, s1 = 0.f;
#pragma unroll
        for (int b = 0; b < 8; b++) {
            unsigned int v = h0[base + b * strd];
            s0 += bf2f((unsigned short)(v & 0xffff));
            s1 += bf2f((unsigned short)(v >> 16));
        }
        unsigned int mv = (unsigned int)f2bf(s0 * 0.125f) |
                          ((unsigned int)f2bf(s1 * 0.125f) << 16);
#pragma unroll
        for (int b = 0; b < 8; b++) h0[base + b * strd] = mv;
        return;
    }
    idx -= 262144;
    if (idx < 131072) {  // l0 c
        int s4 = idx & 3, cell = (idx >> 2) & 255, no = idx >> 10;
        float4* C = (float4*)c0;
        size_t base = ((size_t)no * 256 + cell) * 8 + s4;
        const size_t strd = (size_t)128 * 256 * 8;
        float4 a = {0.f, 0.f, 0.f, 0.f};
#pragma unroll
        for (int b = 0; b < 8; b++) {
            float4 v = C[base + b * strd];
            a.x += v.x; a.y += v.y; a.z += v.z; a.w += v.w;
        }
        a.x *= 0.125f; a.y *= 0.125f; a.z *= 0.125f; a.w *= 0.125f;
#pragma unroll
        for (int b = 0; b < 8; b++) C[base + b * strd] = a;
        return;
    }
    idx -= 131072;
    if (idx < 65536) {  // l1 h
        int u = idx & 7, cell = (idx >> 3) & 127, no = idx >> 10;
        size_t base = ((size_t)no * 128 + cell) * 16 + u;
        const size_t strd = (size_t)64 * 128 * 16;
        float s0 = 0.f, s1 = 0.f;
#pragma unroll
        for (int b = 0; b < 8; b++) {
            unsigned int v = h1[base + b * strd];
            s0 += bf2f((unsigned short)(v & 0xffff));
            s1 += bf2f((unsigned short)(v >> 16));
        }
        unsigned int mv = (unsigned int)f2bf(s0 * 0.125f) |
                          ((unsigned int)f2bf(s1 * 0.125f) << 16);
#pragma unroll
        for (int b = 0; b < 8; b++) h1[base + b * strd] = mv;
        return;
    }
    idx -= 65536;
    if (idx < 32768) {  // l1 c
        int s4 = idx & 3, cell = (idx >> 2) & 127, no = idx >> 9;
        float4* C = (float4*)c1;
        size_t base = ((size_t)no * 128 + cell) * 8 + s4;
        const size_t strd = (size_t)64 * 128 * 8;
        float4 a = {0.f, 0.f, 0.f, 0.f};
#pragma unroll
        for (int b = 0; b < 8; b++) {
            float4 v = C[base + b * strd];
            a.x += v.x; a.y += v.y; a.z += v.z; a.w += v.w;
        }
        a.x *= 0.125f; a.y *= 0.125f; a.z *= 0.125f; a.w *= 0.125f;
#pragma unroll
        for (int b = 0; b < 8; b++) C[base + b * strd] = a;
    }
}

// ---------------------------------------------------------------------------
// Layer 0 (MFMA): block = (b,no), 256 threads = 4 waves, M=256 cells,
// N=128 gates, K=32.  Wave w owns m-tiles 4w..4w+3.
// D layout (m89-verified): row(cell)=(l>>4)*4+reg, col(gate)=l&15.
// ---------------------------------------------------------------------------
__global__ __launch_bounds__(256) void k_l0(
    const float* __restrict__ inp, const float* __restrict__ Wi,
    const unsigned short* __restrict__ WhBp, const float* __restrict__ b_lstm,
    const unsigned short* __restrict__ WfBp, const float* __restrict__ bf_,
    const float* __restrict__ ln_fs, const float* __restrict__ ln_fb,
    unsigned short* __restrict__ h0bf, float* __restrict__ c0g,
    const float* __restrict__ nb1, float* __restrict__ nfsum, int t) {
    int no = blockIdx.x & 127;
    int b = blockIdx.x >> 7;
    int tid = threadIdx.x;
    int w = __builtin_amdgcn_readfirstlane(tid >> 6);
    int l = tid & 63, lo = l & 15, hg = l >> 4;

    __shared__ unsigned short Hbf[256 * 40];   // row pad 40 -> 80B stride
    __shared__ unsigned short BW[4096];
    __shared__ unsigned short BFr[512];
    __shared__ float gsh[128];
    __shared__ float mi_l[256];
    __shared__ float wi0[128];
    __shared__ float redn[4][16];

    {
        unsigned int* d = (unsigned int*)BW;
        const unsigned int* s = (const unsigned int*)WhBp;
#pragma unroll
        for (int i = tid; i < 2048; i += 256) d[i] = s[i];
        // FIX (round 8 bug): BFr is 256 u32 — copy with ALL 256 threads,
        // not tid<128 (lanes 32-63 were reading uninitialized LDS).
        ((unsigned int*)BFr)[tid] = ((const unsigned int*)WfBp)[tid];
    }
    if (tid < 128) {
        float acc = b_lstm[tid];
        const float* nbr = nb1 + ((size_t)b * NO0 + no) * MSG;
#pragma unroll
        for (int m = 0; m < MSG; m++) acc += nbr[m] * Wi[(MSG + m) * 128 + tid];
        gsh[tid] = acc;
        wi0[tid] = Wi[tid];
    }
    mi_l[tid] = inp[((size_t)t * BATCH + b) * NI0 + tid];

    // stage H (bf16) : thread = cell
    {
        const unsigned int* hsrc =
            (const unsigned int*)h0bf + ((size_t)(b * NO0 + no) * 256 + tid) * 16;
        unsigned int* hl = (unsigned int*)Hbf;
#pragma unroll
        for (int j = 0; j < 16; j++) hl[tid * 20 + j] = hsrc[j];
    }

    // c state (f32) in VGPRs
    size_t cbase = (size_t)(b * NO0 + no) * 256 * 32;
    float cst[4][4][2];
#pragma unroll
    for (int mi_ = 0; mi_ < 4; mi_++)
#pragma unroll
        for (int r = 0; r < 4; r++) {
            int cell = (w * 4 + mi_) * 16 + hg * 4 + r;
#pragma unroll
            for (int hi = 0; hi < 2; hi++)
                cst[mi_][r][hi] = c0g[cbase + (size_t)cell * 32 + lo + 16 * hi];
        }
    __syncthreads();

    float g8[8], w8[8];
#pragma unroll
    for (int nt = 0; nt < 8; nt++) { g8[nt] = gsh[lo + 16 * nt]; w8[nt] = wi0[lo + 16 * nt]; }
    f32x4 miv[4];
#pragma unroll
    for (int mi_ = 0; mi_ < 4; mi_++)
#pragma unroll
        for (int r = 0; r < 4; r++)
            miv[mi_][r] = mi_l[(w * 4 + mi_) * 16 + hg * 4 + r];

#pragma unroll
    for (int micro = 0; micro < 2; micro++) {
#pragma unroll
        for (int mi_ = 0; mi_ < 4; mi_++) {
            int mt = w * 4 + mi_;
            bf16x8 A = *(const bf16x8*)&Hbf[(mt * 16 + lo) * 40 + hg * 8];
            // even n-tiles (s-half 0)
            f32x4 acc[4];
#pragma unroll
            for (int g = 0; g < 4; g++) {
                int nt = 2 * g;
                bf16x8 B = *(const bf16x8*)&BW[(nt * 64 + l) * 8];
                f32x4 ci = g8[nt] + miv[mi_] * w8[nt];
                acc[g] = __builtin_amdgcn_mfma_f32_16x16x32_bf16(A, B, ci, 0, 0, 0);
            }
#pragma unroll
            for (int r = 0; r < 4; r++) {
                int cell = mt * 16 + hg * 4 + r;
                float cn = sigf(acc[1][r]) * cst[mi_][r][0] + sigf(acc[0][r]) * tanh_apx(acc[2][r]);
                cst[mi_][r][0] = cn;
                float hv = sigf(acc[3][r]) * tanh_apx(cn);
                unsigned short hb = f2bf(hv);
                Hbf[cell * 40 + lo] = hb;
                if (micro == 1) {
                    h0bf[cbase + (size_t)cell * 32 + lo] = hb;
                    c0g[cbase + (size_t)cell * 32 + lo] = cn;
                }
            }
            // odd n-tiles (s-half 1)
#pragma unroll
            for (int g = 0; g < 4; g++) {
                int nt = 2 * g + 1;
                bf16x8 B = *(const bf16x8*)&BW[(nt * 64 + l) * 8];
                f32x4 ci = g8[nt] + miv[mi_] * w8[nt];
                acc[g] = __builtin_amdgcn_mfma_f32_16x16x32_bf16(A, B, ci, 0, 0, 0);
            }
#pragma unroll
            for (int r = 0; r < 4; r++) {
                int cell = mt * 16 + hg * 4 + r;
                float cn = sigf(acc[1][r]) * cst[mi_][r][1] + sigf(acc[0][r]) * tanh_apx(acc[2][r]);
                cst[mi_][r][1] = cn;
                float hv = sigf(acc[3][r]) * tanh_apx(cn);
                unsigned short hb = f2bf(hv);
                Hbf[cell * 40 + lo + 16] = hb;
                if (micro == 1) {
                    h0bf[cbase + (size_t)cell * 32 + lo + 16] = hb;
                    c0g[cbase + (size_t)cell * 32 + lo + 16] = cn;
                }
            }
        }
        __syncthreads();
    }

    // epilogue: fm = LN(h @ Wf + bf); nf raw sums (k_xf divides /256)
    bf16x8 Ff = *(const bf16x8*)&BFr[l * 8];
    float lnfs = ln_fs[lo], lnfb = ln_fb[lo];
    float bfv = bf_[lo];
    f32x4 cif = {bfv, bfv, bfv, bfv};
    float nfp = 0.f;
#pragma unroll
    for (int mi_ = 0; mi_ < 4; mi_++) {
        int mt = w * 4 + mi_;
        bf16x8 A = *(const bf16x8*)&Hbf[(mt * 16 + lo) * 40 + hg * 8];
        f32x4 f = __builtin_amdgcn_mfma_f32_16x16x32_bf16(A, Ff, cif, 0, 0, 0);
#pragma unroll
        for (int r = 0; r < 4; r++) {
            float x = f[r];
            float mean = sum16(x) * 0.0625f;
            float d = x - mean;
            float rs = rsqrtf(sum16(d * d) * 0.0625f + 1e-6f);
            nfp += d * rs * lnfs + lnfb;
        }
    }
    nfp += __shfl_xor(nfp, 16);
    nfp += __shfl_xor(nfp, 32);
    if (l < 16) redn[w][l] = nfp;
    __syncthreads();
    if (tid < 16)
        nfsum[((size_t)b * NO0 + no) * 16 + tid] =
            redn[0][tid] + redn[1][tid] + redn[2][tid] + redn[3][tid];
}

// ---------------------------------------------------------------------------
// k_xf: xf1T[b][gate][ni] = sum_m (nfsum[b][ni][m]/256) * Wi[m][gate]
// ---------------------------------------------------------------------------
__global__ __launch_bounds__(128) void k_xf(const float* __restrict__ nfsum,
                                            const float* __restrict__ Wi,
                                            float* __restrict__ xf1T) {
    int b = blockIdx.x >> 7;
    int k = blockIdx.x & 127;
    int no = threadIdx.x;
    const float* p = nfsum + ((size_t)b * NO0 + no) * MSG;
    float a = 0.f;
#pragma unroll
    for (int m = 0; m < MSG; m++) a += p[m] * Wi[m * 128 + k];
    xf1T[((size_t)b * 128 + k) * 128 + no] = a * (1.f / 256.f);
}

// ---------------------------------------------------------------------------
// Layer 1 (MFMA): block = (b,no1), 256 threads = 4 waves, M=128, N=128, K=32.
// Wave w owns m-tiles 2w, 2w+1.
// ---------------------------------------------------------------------------
__global__ __launch_bounds__(256) void k_l1(
    const float* __restrict__ Wi, const unsigned short* __restrict__ WhBp,
    const float* __restrict__ b_lstm,
    const unsigned short* __restrict__ WfBp, const float* __restrict__ bf_,
    const float* __restrict__ ln_fs, const float* __restrict__ ln_fb,
    const unsigned short* __restrict__ WbBp, const float* __restrict__ bwb,
    const float* __restrict__ ln_bs, const float* __restrict__ ln_bb,
    unsigned short* __restrict__ h1bf, float* __restrict__ c1g,
    const float* __restrict__ xf1T, const float* __restrict__ gradP,
    const float* __restrict__ ohP,
    float* __restrict__ bm_g, float* __restrict__ outsum) {
    int no = blockIdx.x & 63;
    int b = blockIdx.x >> 6;
    int tid = threadIdx.x;
    int w = __builtin_amdgcn_readfirstlane(tid >> 6);
    int l = tid & 63, lo = l & 15, hg = l >> 4;

    __shared__ unsigned short Hbf[128 * 40];
    __shared__ unsigned short BW[4096];
    __shared__ unsigned short BFr[512];
    __shared__ unsigned short BBr[512];
    __shared__ float gsh[128];
    __shared__ float red[4];

    {
        unsigned int* d = (unsigned int*)BW;
        const unsigned int* s = (const unsigned int*)WhBp;
#pragma unroll
        for (int i = tid; i < 2048; i += 256) d[i] = s[i];
        // FIX (round 8 bug): full 256-u32 copies for BOTH fragment buffers.
        ((unsigned int*)BFr)[tid] = ((const unsigned int*)WfBp)[tid];
        ((unsigned int*)BBr)[tid] = ((const unsigned int*)WbBp)[tid];
    }
    if (tid < 128) {
        float g = gradP[b * NO1 + no], oh = ohP[b * NO1 + no];
        gsh[tid] = b_lstm[tid] + g * Wi[MSG * 128 + tid] + oh * Wi[(MSG + 1) * 128 + tid];
    }

    // stage H: 2 threads per cell
    {
        int cell = tid >> 1, half = tid & 1;
        const unsigned int* hsrc =
            (const unsigned int*)h1bf + ((size_t)(b * NO1 + no) * 128 + cell) * 16 + half * 8;
        unsigned int* hl = (unsigned int*)Hbf;
#pragma unroll
        for (int j = 0; j < 8; j++) hl[cell * 20 + half * 8 + j] = hsrc[j];
    }

    size_t cbase = (size_t)(b * NO1 + no) * 128 * 32;
    float cst[2][4][2];
#pragma unroll
    for (int mi_ = 0; mi_ < 2; mi_++)
#pragma unroll
        for (int r = 0; r < 4; r++) {
            int cell = (w * 2 + mi_) * 16 + hg * 4 + r;
#pragma unroll
            for (int hi = 0; hi < 2; hi++)
                cst[mi_][r][hi] = c1g[cbase + (size_t)cell * 32 + lo + 16 * hi];
        }
    __syncthreads();

    float g8[8];
#pragma unroll
    for (int nt = 0; nt < 8; nt++) g8[nt] = gsh[lo + 16 * nt];
    const float* xfb = xf1T + (size_t)b * 128 * 128;

#pragma unroll
    for (int micro = 0; micro < 2; micro++) {
#pragma unroll
        for (int mi_ = 0; mi_ < 2; mi_++) {
            int mt = w * 2 + mi_;
            bf16x8 A = *(const bf16x8*)&Hbf[(mt * 16 + lo) * 40 + hg * 8];
            f32x4 acc[4];
#pragma unroll
            for (int g = 0; g < 4; g++) {
                int nt = 2 * g;
                bf16x8 B = *(const bf16x8*)&BW[(nt * 64 + l) * 8];
                float4 x4 = *(const float4*)&xfb[(size_t)(lo + 16 * nt) * 128 + mt * 16 + hg * 4];
                f32x4 ci = {g8[nt] + x4.x, g8[nt] + x4.y, g8[nt] + x4.z, g8[nt] + x4.w};
                acc[g] = __builtin_amdgcn_mfma_f32_16x16x32_bf16(A, B, ci, 0, 0, 0);
            }
#pragma unroll
            for (int r = 0; r < 4; r++) {
                int cell = mt * 16 + hg * 4 + r;
                float cn = sigf(acc[1][r]) * cst[mi_][r][0] + sigf(acc[0][r]) * tanh_apx(acc[2][r]);
                cst[mi_][r][0] = cn;
                float hv = sigf(acc[3][r]) * tanh_apx(cn);
                unsigned short hb = f2bf(hv);
                Hbf[cell * 40 + lo] = hb;
                if (micro == 1) {
                    h1bf[cbase + (size_t)cell * 32 + lo] = hb;
                    c1g[cbase + (size_t)cell * 32 + lo] = cn;
                }
            }
#pragma unroll
            for (int g = 0; g < 4; g++) {
                int nt = 2 * g + 1;
                bf16x8 B = *(const bf16x8*)&BW[(nt * 64 + l) * 8];
                float4 x4 = *(const float4*)&xfb[(size_t)(lo + 16 * nt) * 128 + mt * 16 + hg * 4];
                f32x4 ci = {g8[nt] + x4.x, g8[nt] + x4.y, g8[nt] + x4.z, g8[nt] + x4.w};
                acc[g] = __builtin_amdgcn_mfma_f32_16x16x32_bf16(A, B, ci, 0, 0, 0);
            }
#pragma unroll
            for (int r = 0; r < 4; r++) {
                int cell = mt * 16 + hg * 4 + r;
                float cn = sigf(acc[1][r]) * cst[mi_][r][1] + sigf(acc[0][r]) * tanh_apx(acc[2][r]);
                cst[mi_][r][1] = cn;
                float hv = sigf(acc[3][r]) * tanh_apx(cn);
                unsigned short hb = f2bf(hv);
                Hbf[cell * 40 + lo + 16] = hb;
                if (micro == 1) {
                    h1bf[cbase + (size_t)cell * 32 + lo + 16] = hb;
                    c1g[cbase + (size_t)cell * 32 + lo + 16] = cn;
                }
            }
        }
        __syncthreads();
    }

    // epilogue: fm (channel 0 -> outsum) and bm (-> bm_g)
    bf16x8 Ff = *(const bf16x8*)&BFr[l * 8];
    bf16x8 Bb = *(const bf16x8*)&BBr[l * 8];
    float lnfs = ln_fs[lo], lnfb = ln_fb[lo];
    float lnbs = ln_bs[lo], lnbb = ln_bb[lo];
    float bfv = bf_[lo], bwv = bwb[lo];
    f32x4 cif = {bfv, bfv, bfv, bfv};
    f32x4 cib = {bwv, bwv, bwv, bwv};
    float op = 0.f;
#pragma unroll
    for (int mi_ = 0; mi_ < 2; mi_++) {
        int mt = w * 2 + mi_;
        bf16x8 A = *(const bf16x8*)&Hbf[(mt * 16 + lo) * 40 + hg * 8];
        f32x4 f = __builtin_amdgcn_mfma_f32_16x16x32_bf16(A, Ff, cif, 0, 0, 0);
        f32x4 g = __builtin_amdgcn_mfma_f32_16x16x32_bf16(A, Bb, cib, 0, 0, 0);
#pragma unroll
        for (int r = 0; r < 4; r++) {
            int cell = mt * 16 + hg * 4 + r;
            {
                float x = f[r];
                float mean = sum16(x) * 0.0625f;
                float d = x - mean;
                float rs = rsqrtf(sum16(d * d) * 0.0625f + 1e-6f);
                op += d * rs * lnfs + lnfb;
            }
            {
                float x = g[r];
                float mean = sum16(x) * 0.0625f;
                float d = x - mean;
                float rs = rsqrtf(sum16(d * d) * 0.0625f + 1e-6f);
                bm_g[(((size_t)b * NO1 + no) * MSG + lo) * NI1 + cell] = d * rs * lnbs + lnbb;
            }
        }
    }
    op += __shfl_xor(op, 16);
    op += __shfl_xor(op, 32);
    if (l == 0) red[w] = op;
    __syncthreads();
    if (tid == 0)
        outsum[b * NO1 + no] = (red[0] + red[1] + red[2] + red[3]) * (1.f / 128.f);
}

// ---------------------------------------------------------------------------
// nb1[b,ni,m] = mean over no of bm_g
// ---------------------------------------------------------------------------
__global__ void k_red1(const float* __restrict__ bm_g, float* __restrict__ nb1) {
    int g = blockIdx.x * 256 + threadIdx.x;  // < 8*128*16 = 16384
    int ni = g & 127;
    int m = (g >> 7) & 15;
    int b = g >> 11;
    float a = 0.f;
#pragma unroll 8
    for (int no = 0; no < NO1; no++)
        a += bm_g[(((size_t)b * NO1 + no) * MSG + m) * NI1 + ni];
    nb1[((size_t)b * NI1 + ni) * MSG + m] = a * (1.f / NO1);
}

// ---------------------------------------------------------------------------
// out/softmax/error: block per b (64 threads = classes)
// ---------------------------------------------------------------------------
__global__ void k_out(const float* __restrict__ outsum, const int* __restrict__ labels,
                      float* __restrict__ dout, float* __restrict__ gradP,
                      float* __restrict__ ohP, int t) {
    int b = blockIdx.x;
    int no = threadIdx.x;
    float v = outsum[b * NO1 + no];
    float mx = v;
#pragma unroll
    for (int d = 1; d < 64; d <<= 1) mx = fmaxf(mx, __shfl_xor(mx, d));
    float e = __expf(v - mx);
    float sum = e;
#pragma unroll
    for (int d = 1; d < 64; d <<= 1) sum += __shfl_xor(sum, d);
    int lbl = labels[t * BATCH + b];
    float oh = (no == lbl) ? 1.f : 0.f;
    gradP[b * NO1 + no] = e / sum - oh;
    ohP[b * NO1 + no] = oh;
    dout[((size_t)t * BATCH + b) * NO1 + no] = v;
}

// ---------------------------------------------------------------------------

extern "C" void kernel_launch(void* const* d_in, const int* in_sizes, int n_in,
                              void* d_out, int out_size, void* d_ws, size_t ws_size,
                              hipStream_t stream) {
    const float* inp   = (const float*)d_in[0];
    const int*   labels= (const int*)d_in[1];
    const float* Wi    = (const float*)d_in[2];
    const float* Wh    = (const float*)d_in[3];
    const float* b_lstm= (const float*)d_in[4];
    const float* Wf    = (const float*)d_in[5];
    const float* bf_   = (const float*)d_in[6];
    const float* Wb    = (const float*)d_in[7];
    const float* bwb   = (const float*)d_in[8];
    const float* ln_fs = (const float*)d_in[9];
    const float* ln_fb = (const float*)d_in[10];
    const float* ln_bs = (const float*)d_in[11];
    const float* ln_bb = (const float*)d_in[12];
    float* out = (float*)d_out;

    float* w = (float*)d_ws;
    const size_t SZ0 = (size_t)BATCH * NO0 * 256 * 32;  // 8,388,608
    const size_t SZ1 = (size_t)BATCH * NO1 * 128 * 32;  // 2,097,152
    float* c0     = w;
    float* c1     = c0 + SZ0;
    float* xf1T   = c1 + SZ1;                           // 8*128*128
    float* bm_g   = xf1T + (size_t)BATCH * 128 * 128;   // 8*64*16*128
    float* nb1    = bm_g + (size_t)BATCH * NO1 * MSG * NI1;
    float* nfsum  = nb1 + (size_t)BATCH * NI1 * MSG;    // 8*128*16
    float* outsum = nfsum + (size_t)BATCH * NO0 * MSG;  // 512
    float* gradP  = outsum + BATCH * NO1;
    float* ohP    = gradP + BATCH * NO1;
    unsigned short* h0bf = (unsigned short*)(ohP + BATCH * NO1);
    unsigned short* h1bf = h0bf + SZ0;
    unsigned short* WhBp = h1bf + SZ1;
    unsigned short* WfBp = WhBp + 4096;
    unsigned short* WbBp = WfBp + 512;
    size_t total_bytes = (size_t)((char*)(WbBp + 512) - (char*)d_ws);

    hipMemsetAsync(d_ws, 0, total_bytes, stream);
    k_prep<<<20, 256, 0, stream>>>(Wh, Wf, Wb, WhBp, WfBp, WbBp);

    for (int t = 0; t < TSTEPS; t++) {
        if (t) k_merge<<<1920, 256, 0, stream>>>((unsigned int*)h0bf, c0,
                                                 (unsigned int*)h1bf, c1);
        k_l0<<<BATCH * NO0, 256, 0, stream>>>(inp, Wi, WhBp, b_lstm, WfBp, bf_,
                                              ln_fs, ln_fb, h0bf, c0, nb1, nfsum, t);
        k_xf<<<BATCH * 128, 128, 0, stream>>>(nfsum, Wi, xf1T);
        k_l1<<<BATCH * NO1, 256, 0, stream>>>(Wi, WhBp, b_lstm, WfBp, bf_, ln_fs, ln_fb,
                                              WbBp, bwb, ln_bs, ln_bb,
                                              h1bf, c1, xf1T, gradP, ohP, bm_g, outsum);
        k_red1<<<64, 256, 0, stream>>>(bm_g, nb1);
        k_out<<<BATCH, NO1, 0, stream>>>(outsum, labels, out, gradP, ohP, t);
    }
}